// Round 6
// baseline (304.183 us; speedup 1.0000x reference)
//
#include <hip/hip_runtime.h>
#include <hip/hip_bf16.h>

#define B_ 2
#define T_ 4096
#define C_ 512
#define P_ 64
#define PS_ 16
#define CS_ 5
#define MB_ 128
#define FD_ 128

using f32x4 = __attribute__((ext_vector_type(4))) float;
using s16x8 = __attribute__((ext_vector_type(8))) short;

static __device__ __forceinline__ float bf_lo(unsigned u) {
  return __uint_as_float(u << 16);
}
static __device__ __forceinline__ float bf_hi(unsigned u) {
  return __uint_as_float(u & 0xffff0000u);
}
static __device__ __forceinline__ float rdlane_f(float v, int p) {
  return __uint_as_float((unsigned)__builtin_amdgcn_readlane((int)__float_as_uint(v), p));
}
// RNE float -> bf16 bits
static __device__ __forceinline__ ushort bf16u(float f) {
  unsigned x = __float_as_uint(f);
  unsigned r = (x + 0x7fffu + ((x >> 16) & 1u)) >> 16;
  return (ushort)r;
}

// ---- k_prep: ycp[row][8] = bf16(y @ W_proj_comp); weight conversions ------
// blocks 0..255: ycp rows. blocks 256..319: Wp2T/WFT transpose+cvt, WB cvt.
__global__ __launch_bounds__(256) void k_prep(const float* __restrict__ y,
                                              const float* __restrict__ Wc,
                                              const float* __restrict__ Wp2,
                                              const float* __restrict__ WF,
                                              const float* __restrict__ WB,
                                              ushort* __restrict__ ycp,
                                              ushort* __restrict__ Wp2T,
                                              ushort* __restrict__ WFT,
                                              ushort* __restrict__ WBb) {
  const int bx = blockIdx.x;
  const int tid = threadIdx.x;
  if (bx >= 256) {
    // weights: Wp2T (65536) + WFT (16384) + WBb (5120) = 87040 elems
    for (int id = (bx - 256) * 256 + tid; id < 87040; id += 64 * 256) {
      if (id < 65536) {
        const int c = id >> 7, m = id & 127;
        Wp2T[(size_t)m * C_ + c] = bf16u(Wp2[id]);
      } else if (id < 81920) {
        const int i2 = id - 65536;
        const int m = i2 >> 7, f = i2 & 127;
        WFT[(size_t)f * MB_ + m] = bf16u(WF[i2]);
      } else {
        const int i3 = id - 81920;
        WBb[i3] = bf16u(WB[i3]);
      }
    }
    return;
  }
  const int lane = tid & 63;
  const int wid  = tid >> 6;
  float wc[40];
  {
    const float4* src = (const float4*)(Wc + lane * 40);
    #pragma unroll
    for (int j = 0; j < 10; j++) {
      float4 v = src[j];
      wc[j*4+0] = v.x; wc[j*4+1] = v.y; wc[j*4+2] = v.z; wc[j*4+3] = v.w;
    }
  }
  const int row_base = (bx * 4 + wid) * 8;
  #pragma unroll 2
  for (int r = 0; r < 8; r++) {
    const int row = row_base + r;                       // 0..8191 = b*T+t
    const float4* yr = (const float4*)(y + (size_t)row * C_ + lane * 8);
    float4 a = yr[0], b4 = yr[1];
    float e[8] = {a.x, a.y, a.z, a.w, b4.x, b4.y, b4.z, b4.w};
    float s0 = 0.f, s1 = 0.f, s2 = 0.f, s3 = 0.f, s4 = 0.f;
    #pragma unroll
    for (int j = 0; j < 8; j++) {
      s0 = fmaf(e[j], wc[j*5+0], s0);
      s1 = fmaf(e[j], wc[j*5+1], s1);
      s2 = fmaf(e[j], wc[j*5+2], s2);
      s3 = fmaf(e[j], wc[j*5+3], s3);
      s4 = fmaf(e[j], wc[j*5+4], s4);
    }
    #pragma unroll
    for (int off = 1; off < 64; off <<= 1) {
      s0 += __shfl_xor(s0, off); s1 += __shfl_xor(s1, off);
      s2 += __shfl_xor(s2, off); s3 += __shfl_xor(s3, off);
      s4 += __shfl_xor(s4, off);
    }
    float myv = (lane == 0) ? s0 : (lane == 1) ? s1 : (lane == 2) ? s2
              : (lane == 3) ? s3 : (lane == 4) ? s4 : 0.f;
    if (lane < 8) ycp[(size_t)row * 8 + lane] = bf16u(myv);
  }
}

// ---- k_gemm: C[M][128] = A[M][K] @ Bt[128][K]^T  (bf16 MFMA, fp32 accum) ---
// BM=32, BN=64, BK=64; 4 waves 2x2 (wave tile 16x32); XOR-swizzled LDS.
// A_F32: stage A from fp32 source, converting to bf16 on the fly.
template<int KTOT, bool OUTBF, bool A_F32>
__global__ __launch_bounds__(256) void k_gemm(const void* __restrict__ Asrc,
                                              const ushort* __restrict__ Bt,
                                              void* __restrict__ Cout) {
  __shared__ __align__(16) char smem[(32 + 64) * 128];  // A 4KB @0, B 8KB @4096
  const int tid  = threadIdx.x;
  const int lane = tid & 63;
  const int wid  = tid >> 6;
  const int wm = wid >> 1, wn = wid & 1;
  const int rowA0 = (blockIdx.x >> 1) * 32;
  const int bn    = blockIdx.x & 1;

  f32x4 acc[2];
  acc[0] = (f32x4){0.f, 0.f, 0.f, 0.f};
  acc[1] = (f32x4){0.f, 0.f, 0.f, 0.f};

  for (int step = 0; step < KTOT / 64; step++) {
    const int kc = step * 64;
    // stage to regs first (overlap with previous compute)
    uint4 ra;  // 8 bf16 of A
    {
      const int r = tid >> 3, sl = tid & 7;   // 256 slots: 32 rows x 8
      if (A_F32) {
        const float4* ap = (const float4*)((const float*)Asrc +
                            (size_t)(rowA0 + r) * KTOT + kc + sl * 8);
        float4 f0 = ap[0], f1 = ap[1];
        union { ushort us[8]; uint4 q; } pk;
        pk.us[0] = bf16u(f0.x); pk.us[1] = bf16u(f0.y);
        pk.us[2] = bf16u(f0.z); pk.us[3] = bf16u(f0.w);
        pk.us[4] = bf16u(f1.x); pk.us[5] = bf16u(f1.y);
        pk.us[6] = bf16u(f1.z); pk.us[7] = bf16u(f1.w);
        ra = pk.q;
      } else {
        ra = *(const uint4*)((const ushort*)Asrc +
                             (size_t)(rowA0 + r) * KTOT + kc + sl * 8);
      }
    }
    uint4 rb[2];
    #pragma unroll
    for (int i = 0; i < 2; i++) {
      const int slot = tid + i * 256, r = slot >> 3, sl = slot & 7;
      rb[i] = *(const uint4*)(Bt + (size_t)(bn * 64 + r) * KTOT + kc + sl * 8);
    }
    __syncthreads();   // previous compute done before overwrite
    {
      const int r = tid >> 3, sl = tid & 7;
      *(uint4*)(smem + r * 128 + ((sl * 16) ^ ((r & 7) << 4))) = ra;
    }
    #pragma unroll
    for (int i = 0; i < 2; i++) {
      const int slot = tid + i * 256, r = slot >> 3, sl = slot & 7;
      *(uint4*)(smem + 4096 + r * 128 + ((sl * 16) ^ ((r & 7) << 4))) = rb[i];
    }
    __syncthreads();
    #pragma unroll
    for (int kk = 0; kk < 2; kk++) {
      const int cb = kk * 64 + (lane >> 4) * 16;
      const int r = wm * 16 + (lane & 15);
      s16x8 a = *(const s16x8*)(smem + r * 128 + (cb ^ ((r & 7) << 4)));
      #pragma unroll
      for (int n = 0; n < 2; n++) {
        const int rn = wn * 32 + n * 16 + (lane & 15);
        s16x8 b = *(const s16x8*)(smem + 4096 + rn * 128 + (cb ^ ((rn & 7) << 4)));
        acc[n] = __builtin_amdgcn_mfma_f32_16x16x32_bf16(a, b, acc[n], 0, 0, 0);
      }
    }
  }
  // epilogue: row=(lane>>4)*4+reg (M), col=lane&15 (N)
  #pragma unroll
  for (int n = 0; n < 2; n++) {
    #pragma unroll
    for (int reg = 0; reg < 4; reg++) {
      const int grow = rowA0 + wm * 16 + (lane >> 4) * 4 + reg;
      const int gcol = bn * 64 + wn * 32 + n * 16 + (lane & 15);
      if (OUTBF)
        ((ushort*)Cout)[(size_t)grow * 128 + gcol] = bf16u(acc[n][reg]);
      else
        ((float*)Cout)[(size_t)grow * 128 + gcol] = acc[n][reg];
    }
  }
}

// ---- k_mid: wave-per-t; WB bf16-packed in regs, Wps1 in LDS (spill-free) --
__global__ __launch_bounds__(256, 4) void k_mid(
    const ushort* __restrict__ ycp,   // [B][T][8] bf16
    const ushort* __restrict__ bmb,   // [B][T][MB] bf16
    const ushort* __restrict__ WBb,   // [P][PS*CS] bf16
    const float* __restrict__ Wbias,  // [P]
    const float* __restrict__ Wps1,   // [P][P]
    const int* __restrict__ patches,  // [T][P][PS]
    const int* __restrict__ pproj,    // [T][P]
    ushort* __restrict__ obmb)        // [B][T][MB] bf16
{
  __shared__ __align__(16) float wps[64 * 64];  // 16KB: Wps1 staged per block
  const int tid  = threadIdx.x;
  const int lane = tid & 63;
  const int wid  = tid >> 6;
  const int gw   = blockIdx.x * 4 + wid;      // 0..2047

  for (int j = tid; j < 1024; j += 256)
    ((float4*)wps)[j] = ((const float4*)Wps1)[j];
  __syncthreads();

  // WB row for patch `lane`: 80 bf16 = 40 packed u32 (10 uint4 loads)
  union { unsigned u[40]; uint4 q[10]; } wbu;
  {
    const uint4* src = (const uint4*)(WBb + lane * 80);
    #pragma unroll
    for (int j = 0; j < 10; j++) wbu.q[j] = src[j];
  }
  const float bias = Wbias[lane];

  #pragma unroll 1
  for (int tt = 0; tt < 2; tt++) {
    const int t = gw * 2 + tt;                // 0..4095
    int idx[16];
    {
      const int4* psrc = (const int4*)(patches + (size_t)t * P_ * PS_ + lane * PS_);
      #pragma unroll
      for (int j = 0; j < 4; j++) {
        int4 v = psrc[j];
        idx[j*4+0] = v.x; idx[j*4+1] = v.y; idx[j*4+2] = v.z; idx[j*4+3] = v.w;
      }
    }
    const int pp = pproj[(size_t)t * P_ + lane];

    #pragma unroll 1
    for (int b = 0; b < B_; b++) {
      const ushort* yb = ycp + (size_t)b * T_ * 8;
      // res: gather 16 padded yc rows, dot with bf16 WB row (5 parallel chains)
      float c0 = bias, c1 = 0.f, c2 = 0.f, c3 = 0.f, c4 = 0.f;
      #pragma unroll
      for (int s = 0; s < 16; s++) {
        uint4 g = *(const uint4*)(yb + (size_t)idx[s] * 8);
        const int e = s * 5;  // element base (compile-time)
        const float w0 = ((e+0)&1) ? bf_hi(wbu.u[(e+0)>>1]) : bf_lo(wbu.u[(e+0)>>1]);
        const float w1 = ((e+1)&1) ? bf_hi(wbu.u[(e+1)>>1]) : bf_lo(wbu.u[(e+1)>>1]);
        const float w2 = ((e+2)&1) ? bf_hi(wbu.u[(e+2)>>1]) : bf_lo(wbu.u[(e+2)>>1]);
        const float w3 = ((e+3)&1) ? bf_hi(wbu.u[(e+3)>>1]) : bf_lo(wbu.u[(e+3)>>1]);
        const float w4 = ((e+4)&1) ? bf_hi(wbu.u[(e+4)>>1]) : bf_lo(wbu.u[(e+4)>>1]);
        c0 = fmaf(bf_lo(g.x), w0, c0);
        c1 = fmaf(bf_hi(g.x), w1, c1);
        c2 = fmaf(bf_lo(g.y), w2, c2);
        c3 = fmaf(bf_hi(g.y), w3, c3);
        c4 = fmaf(bf_lo(g.z), w4, c4);
      }
      const float sum = (c0 + c1) + (c2 + c3) + c4;
      // mix[lane] = sum_p res[p] * Wps1[p][lane] (4 chains; Wps1 from LDS)
      float m0 = 0.f, m1 = 0.f, m2 = 0.f, m3 = 0.f;
      #pragma unroll
      for (int p = 0; p < 64; p += 4) {
        m0 = fmaf(rdlane_f(sum, p + 0), wps[(p + 0) * 64 + lane], m0);
        m1 = fmaf(rdlane_f(sum, p + 1), wps[(p + 1) * 64 + lane], m1);
        m2 = fmaf(rdlane_f(sum, p + 2), wps[(p + 2) * 64 + lane], m2);
        m3 = fmaf(rdlane_f(sum, p + 3), wps[(p + 3) * 64 + lane], m3);
      }
      const float mix = (m0 + m1) + (m2 + m3);
      // out[m]: lane handles m = 2*lane, 2*lane+1 (2 parallel chains each)
      const ushort* bb = bmb + (size_t)b * T_ * MB_;
      float oxa = 0.f, oya = 0.f, oxb = 0.f, oyb = 0.f;
      #pragma unroll
      for (int p = 0; p < 64; p += 2) {
        const float mpa = rdlane_f(mix, p);
        const int rowa = __builtin_amdgcn_readlane(pp, p);
        unsigned va = *(const unsigned*)(bb + (size_t)rowa * MB_ + lane * 2);
        oxa = fmaf(bf_lo(va), mpa, oxa);
        oya = fmaf(bf_hi(va), mpa, oya);
        const float mpb = rdlane_f(mix, p + 1);
        const int rowb = __builtin_amdgcn_readlane(pp, p + 1);
        unsigned vb = *(const unsigned*)(bb + (size_t)rowb * MB_ + lane * 2);
        oxb = fmaf(bf_lo(vb), mpb, oxb);
        oyb = fmaf(bf_hi(vb), mpb, oyb);
      }
      unsigned pkd = (unsigned)bf16u(oxa + oxb) | ((unsigned)bf16u(oya + oyb) << 16);
      *(unsigned*)(obmb + ((size_t)b * T_ + t) * MB_ + lane * 2) = pkd;
    }
  }
}

extern "C" void kernel_launch(void* const* d_in, const int* in_sizes, int n_in,
                              void* d_out, int out_size, void* d_ws, size_t ws_size,
                              hipStream_t stream) {
  const float* y     = (const float*)d_in[0];
  const float* WB    = (const float*)d_in[1];
  const float* Wbias = (const float*)d_in[2];
  const float* Wp2   = (const float*)d_in[3];
  const float* Wpc   = (const float*)d_in[4];
  const float* Wps1  = (const float*)d_in[5];
  const float* WF    = (const float*)d_in[6];
  const int* patches = (const int*)d_in[7];
  const int* pproj   = (const int*)d_in[8];
  float* out = (float*)d_out;

  char* ws = (char*)d_ws;
  ushort* bmb  = (ushort*)(ws);                 // 2 MB    [2][4096][128]
  ushort* obmb = (ushort*)(ws + 2097152);       // 2 MB    [2][4096][128]
  ushort* ycp  = (ushort*)(ws + 4194304);       // 128 KB  [2][4096][8]
  ushort* Wp2T = (ushort*)(ws + 4325376);       // 128 KB  [128][512]
  ushort* WFT  = (ushort*)(ws + 4456448);       // 32 KB   [128][128]
  ushort* WBb  = (ushort*)(ws + 4489216);       // 10 KB   [64][80]

  k_prep<<<dim3(320), dim3(256), 0, stream>>>(y, Wpc, Wp2, WF, WB,
                                              ycp, Wp2T, WFT, WBb);
  k_gemm<512, true,  true ><<<dim3(512), dim3(256), 0, stream>>>((const void*)y, Wp2T, (void*)bmb);
  k_mid <<<dim3(512), dim3(256), 0, stream>>>(ycp, bmb, WBb, Wbias, Wps1,
                                              patches, pproj, obmb);
  k_gemm<128, false, false><<<dim3(512), dim3(256), 0, stream>>>((const void*)obmb, WFT, (void*)out);
}

// Round 7
// 267.051 us; speedup vs baseline: 1.1390x; 1.1390x over previous
//
#include <hip/hip_runtime.h>
#include <hip/hip_bf16.h>

#define B_ 2
#define T_ 4096
#define C_ 512
#define P_ 64
#define PS_ 16
#define CS_ 5
#define MB_ 128
#define FD_ 128

using f32x4 = __attribute__((ext_vector_type(4))) float;
using s16x8 = __attribute__((ext_vector_type(8))) short;
using i32x4 = __attribute__((ext_vector_type(4))) int;

static __device__ __forceinline__ float bf_lo(unsigned u) {
  return __uint_as_float(u << 16);
}
static __device__ __forceinline__ float bf_hi(unsigned u) {
  return __uint_as_float(u & 0xffff0000u);
}
static __device__ __forceinline__ float rdlane_f(float v, int p) {
  return __uint_as_float((unsigned)__builtin_amdgcn_readlane((int)__float_as_uint(v), p));
}
// RNE float -> bf16 bits
static __device__ __forceinline__ ushort bf16u(float f) {
  unsigned x = __float_as_uint(f);
  unsigned r = (x + 0x7fffu + ((x >> 16) & 1u)) >> 16;
  return (ushort)r;
}

// ---- k_prep: ycp[row][8] = bf16(y @ W_proj_comp); weight conversions ------
// blocks 0..255: ycp rows. blocks 256..319: Wp2T/WFT transpose+cvt, WB cvt.
__global__ __launch_bounds__(256) void k_prep(const float* __restrict__ y,
                                              const float* __restrict__ Wc,
                                              const float* __restrict__ Wp2,
                                              const float* __restrict__ WF,
                                              const float* __restrict__ WB,
                                              ushort* __restrict__ ycp,
                                              ushort* __restrict__ Wp2T,
                                              ushort* __restrict__ WFT,
                                              ushort* __restrict__ WBb) {
  const int bx = blockIdx.x;
  const int tid = threadIdx.x;
  if (bx >= 256) {
    // weights: Wp2T (65536) + WFT (16384) + WBb (5120) = 87040 elems
    for (int id = (bx - 256) * 256 + tid; id < 87040; id += 64 * 256) {
      if (id < 65536) {
        const int c = id >> 7, m = id & 127;
        Wp2T[(size_t)m * C_ + c] = bf16u(Wp2[id]);
      } else if (id < 81920) {
        const int i2 = id - 65536;
        const int m = i2 >> 7, f = i2 & 127;
        WFT[(size_t)f * MB_ + m] = bf16u(WF[i2]);
      } else {
        const int i3 = id - 81920;
        WBb[i3] = bf16u(WB[i3]);
      }
    }
    return;
  }
  const int lane = tid & 63;
  const int wid  = tid >> 6;
  float wc[40];
  {
    const float4* src = (const float4*)(Wc + lane * 40);
    #pragma unroll
    for (int j = 0; j < 10; j++) {
      float4 v = src[j];
      wc[j*4+0] = v.x; wc[j*4+1] = v.y; wc[j*4+2] = v.z; wc[j*4+3] = v.w;
    }
  }
  const int row_base = (bx * 4 + wid) * 8;
  #pragma unroll 2
  for (int r = 0; r < 8; r++) {
    const int row = row_base + r;                       // 0..8191 = b*T+t
    const float4* yr = (const float4*)(y + (size_t)row * C_ + lane * 8);
    float4 a = yr[0], b4 = yr[1];
    float e[8] = {a.x, a.y, a.z, a.w, b4.x, b4.y, b4.z, b4.w};
    float s0 = 0.f, s1 = 0.f, s2 = 0.f, s3 = 0.f, s4 = 0.f;
    #pragma unroll
    for (int j = 0; j < 8; j++) {
      s0 = fmaf(e[j], wc[j*5+0], s0);
      s1 = fmaf(e[j], wc[j*5+1], s1);
      s2 = fmaf(e[j], wc[j*5+2], s2);
      s3 = fmaf(e[j], wc[j*5+3], s3);
      s4 = fmaf(e[j], wc[j*5+4], s4);
    }
    #pragma unroll
    for (int off = 1; off < 64; off <<= 1) {
      s0 += __shfl_xor(s0, off); s1 += __shfl_xor(s1, off);
      s2 += __shfl_xor(s2, off); s3 += __shfl_xor(s3, off);
      s4 += __shfl_xor(s4, off);
    }
    float myv = (lane == 0) ? s0 : (lane == 1) ? s1 : (lane == 2) ? s2
              : (lane == 3) ? s3 : (lane == 4) ? s4 : 0.f;
    if (lane < 8) ycp[(size_t)row * 8 + lane] = bf16u(myv);
  }
}

// ---- k_gemm: C[M][128] = A[M][K] @ Bt[128][K]^T  (bf16 MFMA, fp32 accum) ---
// BM=32, BN=64, BK=64; 4 waves 2x2 (wave tile 16x32); XOR-swizzled LDS.
// A_F32: stage A from fp32 source, converting to bf16 on the fly.
template<int KTOT, bool OUTBF, bool A_F32>
__global__ __launch_bounds__(256) void k_gemm(const void* __restrict__ Asrc,
                                              const ushort* __restrict__ Bt,
                                              void* __restrict__ Cout) {
  __shared__ __align__(16) char smem[(32 + 64) * 128];  // A 4KB @0, B 8KB @4096
  const int tid  = threadIdx.x;
  const int lane = tid & 63;
  const int wid  = tid >> 6;
  const int wm = wid >> 1, wn = wid & 1;
  const int rowA0 = (blockIdx.x >> 1) * 32;
  const int bn    = blockIdx.x & 1;

  f32x4 acc[2];
  acc[0] = (f32x4){0.f, 0.f, 0.f, 0.f};
  acc[1] = (f32x4){0.f, 0.f, 0.f, 0.f};

  for (int step = 0; step < KTOT / 64; step++) {
    const int kc = step * 64;
    // stage to regs first (overlap with previous compute)
    uint4 ra;  // 8 bf16 of A
    {
      const int r = tid >> 3, sl = tid & 7;   // 256 slots: 32 rows x 8
      if (A_F32) {
        const float4* ap = (const float4*)((const float*)Asrc +
                            (size_t)(rowA0 + r) * KTOT + kc + sl * 8);
        float4 f0 = ap[0], f1 = ap[1];
        union { ushort us[8]; uint4 q; } pk;
        pk.us[0] = bf16u(f0.x); pk.us[1] = bf16u(f0.y);
        pk.us[2] = bf16u(f0.z); pk.us[3] = bf16u(f0.w);
        pk.us[4] = bf16u(f1.x); pk.us[5] = bf16u(f1.y);
        pk.us[6] = bf16u(f1.z); pk.us[7] = bf16u(f1.w);
        ra = pk.q;
      } else {
        ra = *(const uint4*)((const ushort*)Asrc +
                             (size_t)(rowA0 + r) * KTOT + kc + sl * 8);
      }
    }
    uint4 rb[2];
    #pragma unroll
    for (int i = 0; i < 2; i++) {
      const int slot = tid + i * 256, r = slot >> 3, sl = slot & 7;
      rb[i] = *(const uint4*)(Bt + (size_t)(bn * 64 + r) * KTOT + kc + sl * 8);
    }
    __syncthreads();   // previous compute done before overwrite
    {
      const int r = tid >> 3, sl = tid & 7;
      *(uint4*)(smem + r * 128 + ((sl * 16) ^ ((r & 7) << 4))) = ra;
    }
    #pragma unroll
    for (int i = 0; i < 2; i++) {
      const int slot = tid + i * 256, r = slot >> 3, sl = slot & 7;
      *(uint4*)(smem + 4096 + r * 128 + ((sl * 16) ^ ((r & 7) << 4))) = rb[i];
    }
    __syncthreads();
    #pragma unroll
    for (int kk = 0; kk < 2; kk++) {
      const int cb = kk * 64 + (lane >> 4) * 16;
      const int r = wm * 16 + (lane & 15);
      s16x8 a = *(const s16x8*)(smem + r * 128 + (cb ^ ((r & 7) << 4)));
      #pragma unroll
      for (int n = 0; n < 2; n++) {
        const int rn = wn * 32 + n * 16 + (lane & 15);
        s16x8 b = *(const s16x8*)(smem + 4096 + rn * 128 + (cb ^ ((rn & 7) << 4)));
        acc[n] = __builtin_amdgcn_mfma_f32_16x16x32_bf16(a, b, acc[n], 0, 0, 0);
      }
    }
  }
  // epilogue: row=(lane>>4)*4+reg (M), col=lane&15 (N)
  #pragma unroll
  for (int n = 0; n < 2; n++) {
    #pragma unroll
    for (int reg = 0; reg < 4; reg++) {
      const int grow = rowA0 + wm * 16 + (lane >> 4) * 4 + reg;
      const int gcol = bn * 64 + wn * 32 + n * 16 + (lane & 15);
      if (OUTBF)
        ((ushort*)Cout)[(size_t)grow * 128 + gcol] = bf16u(acc[n][reg]);
      else
        ((float*)Cout)[(size_t)grow * 128 + gcol] = acc[n][reg];
    }
  }
}

// ---- k_mid: wave-per-t; nt streams protect L2 residency of bmb/ycp --------
__global__ __launch_bounds__(256, 4) void k_mid(
    const ushort* __restrict__ ycp,   // [B][T][8] bf16   (L2-resident, 128KB)
    const ushort* __restrict__ bmb,   // [B][T][MB] bf16  (L2-resident, 2MB)
    const ushort* __restrict__ WBb,   // [P][PS*CS] bf16
    const float* __restrict__ Wbias,  // [P]
    const float* __restrict__ Wps1,   // [P][P]
    const int* __restrict__ patches,  // [T][P][PS]  (nt stream)
    const int* __restrict__ pproj,    // [T][P]      (nt stream)
    ushort* __restrict__ obmb)        // [B][T][MB] bf16 (nt stream out)
{
  __shared__ __align__(16) float wps[64 * 64];  // 16KB: Wps1 staged per block
  const int tid  = threadIdx.x;
  const int lane = tid & 63;
  const int wid  = tid >> 6;
  const int t    = blockIdx.x * 4 + wid;        // wave-per-t, 0..4095

  for (int j = tid; j < 1024; j += 256)
    ((float4*)wps)[j] = ((const float4*)Wps1)[j];
  __syncthreads();

  // WB row for patch `lane`: 80 bf16 = 40 packed u32 (10 uint4 loads)
  union { unsigned u[40]; uint4 q[10]; } wbu;
  {
    const uint4* src = (const uint4*)(WBb + lane * 80);
    #pragma unroll
    for (int j = 0; j < 10; j++) wbu.q[j] = src[j];
  }
  const float bias = Wbias[lane];

  int idx[16];
  {
    const i32x4* psrc = (const i32x4*)(patches + (size_t)t * P_ * PS_ + lane * PS_);
    #pragma unroll
    for (int j = 0; j < 4; j++) {
      i32x4 v = __builtin_nontemporal_load(psrc + j);
      idx[j*4+0] = v.x; idx[j*4+1] = v.y; idx[j*4+2] = v.z; idx[j*4+3] = v.w;
    }
  }
  const int pp = __builtin_nontemporal_load(pproj + (size_t)t * P_ + lane);

  #pragma unroll 1
  for (int b = 0; b < B_; b++) {
    const ushort* yb = ycp + (size_t)b * T_ * 8;
    // res: gather 16 padded yc rows, dot with bf16 WB row (5 parallel chains)
    float c0 = bias, c1 = 0.f, c2 = 0.f, c3 = 0.f, c4 = 0.f;
    #pragma unroll
    for (int s = 0; s < 16; s++) {
      uint4 g = *(const uint4*)(yb + (size_t)idx[s] * 8);
      const int e = s * 5;  // element base (compile-time)
      const float w0 = ((e+0)&1) ? bf_hi(wbu.u[(e+0)>>1]) : bf_lo(wbu.u[(e+0)>>1]);
      const float w1 = ((e+1)&1) ? bf_hi(wbu.u[(e+1)>>1]) : bf_lo(wbu.u[(e+1)>>1]);
      const float w2 = ((e+2)&1) ? bf_hi(wbu.u[(e+2)>>1]) : bf_lo(wbu.u[(e+2)>>1]);
      const float w3 = ((e+3)&1) ? bf_hi(wbu.u[(e+3)>>1]) : bf_lo(wbu.u[(e+3)>>1]);
      const float w4 = ((e+4)&1) ? bf_hi(wbu.u[(e+4)>>1]) : bf_lo(wbu.u[(e+4)>>1]);
      c0 = fmaf(bf_lo(g.x), w0, c0);
      c1 = fmaf(bf_hi(g.x), w1, c1);
      c2 = fmaf(bf_lo(g.y), w2, c2);
      c3 = fmaf(bf_hi(g.y), w3, c3);
      c4 = fmaf(bf_lo(g.z), w4, c4);
    }
    const float sum = (c0 + c1) + (c2 + c3) + c4;
    // mix[lane] = sum_p res[p] * Wps1[p][lane] (4 chains; Wps1 from LDS)
    float m0 = 0.f, m1 = 0.f, m2 = 0.f, m3 = 0.f;
    #pragma unroll
    for (int p = 0; p < 64; p += 4) {
      m0 = fmaf(rdlane_f(sum, p + 0), wps[(p + 0) * 64 + lane], m0);
      m1 = fmaf(rdlane_f(sum, p + 1), wps[(p + 1) * 64 + lane], m1);
      m2 = fmaf(rdlane_f(sum, p + 2), wps[(p + 2) * 64 + lane], m2);
      m3 = fmaf(rdlane_f(sum, p + 3), wps[(p + 3) * 64 + lane], m3);
    }
    const float mix = (m0 + m1) + (m2 + m3);
    // out[m]: lane handles m = 2*lane, 2*lane+1 (2 parallel chains each)
    const ushort* bb = bmb + (size_t)b * T_ * MB_;
    float oxa = 0.f, oya = 0.f, oxb = 0.f, oyb = 0.f;
    #pragma unroll
    for (int p = 0; p < 64; p += 2) {
      const float mpa = rdlane_f(mix, p);
      const int rowa = __builtin_amdgcn_readlane(pp, p);
      unsigned va = *(const unsigned*)(bb + (size_t)rowa * MB_ + lane * 2);
      oxa = fmaf(bf_lo(va), mpa, oxa);
      oya = fmaf(bf_hi(va), mpa, oya);
      const float mpb = rdlane_f(mix, p + 1);
      const int rowb = __builtin_amdgcn_readlane(pp, p + 1);
      unsigned vb = *(const unsigned*)(bb + (size_t)rowb * MB_ + lane * 2);
      oxb = fmaf(bf_lo(vb), mpb, oxb);
      oyb = fmaf(bf_hi(vb), mpb, oyb);
    }
    unsigned pkd = (unsigned)bf16u(oxa + oxb) | ((unsigned)bf16u(oya + oyb) << 16);
    __builtin_nontemporal_store(pkd,
        (unsigned*)(obmb + ((size_t)b * T_ + t) * MB_ + lane * 2));
  }
}

extern "C" void kernel_launch(void* const* d_in, const int* in_sizes, int n_in,
                              void* d_out, int out_size, void* d_ws, size_t ws_size,
                              hipStream_t stream) {
  const float* y     = (const float*)d_in[0];
  const float* WB    = (const float*)d_in[1];
  const float* Wbias = (const float*)d_in[2];
  const float* Wp2   = (const float*)d_in[3];
  const float* Wpc   = (const float*)d_in[4];
  const float* Wps1  = (const float*)d_in[5];
  const float* WF    = (const float*)d_in[6];
  const int* patches = (const int*)d_in[7];
  const int* pproj   = (const int*)d_in[8];
  float* out = (float*)d_out;

  char* ws = (char*)d_ws;
  ushort* bmb  = (ushort*)(ws);                 // 2 MB    [2][4096][128]
  ushort* obmb = (ushort*)(ws + 2097152);       // 2 MB    [2][4096][128]
  ushort* ycp  = (ushort*)(ws + 4194304);       // 128 KB  [2][4096][8]
  ushort* Wp2T = (ushort*)(ws + 4325376);       // 128 KB  [128][512]
  ushort* WFT  = (ushort*)(ws + 4456448);       // 32 KB   [128][128]
  ushort* WBb  = (ushort*)(ws + 4489216);       // 10 KB   [64][80]

  k_prep<<<dim3(320), dim3(256), 0, stream>>>(y, Wpc, Wp2, WF, WB,
                                              ycp, Wp2T, WFT, WBb);
  k_gemm<512, true,  true ><<<dim3(512), dim3(256), 0, stream>>>((const void*)y, Wp2T, (void*)bmb);
  k_mid <<<dim3(1024), dim3(256), 0, stream>>>(ycp, bmb, WBb, Wbias, Wps1,
                                               patches, pproj, obmb);
  k_gemm<128, false, false><<<dim3(512), dim3(256), 0, stream>>>((const void*)obmb, WFT, (void*)out);
}

// Round 8
// 177.995 us; speedup vs baseline: 1.7089x; 1.5003x over previous
//
#include <hip/hip_runtime.h>
#include <hip/hip_bf16.h>

#define B_ 2
#define T_ 4096
#define C_ 512
#define P_ 64
#define PS_ 16
#define CS_ 5
#define MB_ 128
#define FD_ 128

using f32x4 = __attribute__((ext_vector_type(4))) float;
using s16x8 = __attribute__((ext_vector_type(8))) short;
using i32x4 = __attribute__((ext_vector_type(4))) int;

static __device__ __forceinline__ float bf_lo(unsigned u) {
  return __uint_as_float(u << 16);
}
static __device__ __forceinline__ float bf_hi(unsigned u) {
  return __uint_as_float(u & 0xffff0000u);
}
static __device__ __forceinline__ float rdlane_f(float v, int p) {
  return __uint_as_float((unsigned)__builtin_amdgcn_readlane((int)__float_as_uint(v), p));
}
// RNE float -> bf16 bits
static __device__ __forceinline__ ushort bf16u(float f) {
  unsigned x = __float_as_uint(f);
  unsigned r = (x + 0x7fffu + ((x >> 16) & 1u)) >> 16;
  return (ushort)r;
}

// ---- k_prep: ycp[row][8] = bf16(y @ W_proj_comp); weight conversions ------
// blocks 0..255: ycp rows. blocks 256..319: Wp2T/WFT transpose+cvt, WB cvt.
__global__ __launch_bounds__(256) void k_prep(const float* __restrict__ y,
                                              const float* __restrict__ Wc,
                                              const float* __restrict__ Wp2,
                                              const float* __restrict__ WF,
                                              const float* __restrict__ WB,
                                              ushort* __restrict__ ycp,
                                              ushort* __restrict__ Wp2T,
                                              ushort* __restrict__ WFT,
                                              ushort* __restrict__ WBb) {
  const int bx = blockIdx.x;
  const int tid = threadIdx.x;
  if (bx >= 256) {
    // weights: Wp2T (65536) + WFT (16384) + WBb (5120) = 87040 elems
    for (int id = (bx - 256) * 256 + tid; id < 87040; id += 64 * 256) {
      if (id < 65536) {
        const int c = id >> 7, m = id & 127;
        Wp2T[(size_t)m * C_ + c] = bf16u(Wp2[id]);
      } else if (id < 81920) {
        const int i2 = id - 65536;
        const int m = i2 >> 7, f = i2 & 127;
        WFT[(size_t)f * MB_ + m] = bf16u(WF[i2]);
      } else {
        const int i3 = id - 81920;
        WBb[i3] = bf16u(WB[i3]);
      }
    }
    return;
  }
  const int lane = tid & 63;
  const int wid  = tid >> 6;
  float wc[40];
  {
    const float4* src = (const float4*)(Wc + lane * 40);
    #pragma unroll
    for (int j = 0; j < 10; j++) {
      float4 v = src[j];
      wc[j*4+0] = v.x; wc[j*4+1] = v.y; wc[j*4+2] = v.z; wc[j*4+3] = v.w;
    }
  }
  const int row_base = (bx * 4 + wid) * 8;
  #pragma unroll 2
  for (int r = 0; r < 8; r++) {
    const int row = row_base + r;                       // 0..8191 = b*T+t
    const float4* yr = (const float4*)(y + (size_t)row * C_ + lane * 8);
    float4 a = yr[0], b4 = yr[1];
    float e[8] = {a.x, a.y, a.z, a.w, b4.x, b4.y, b4.z, b4.w};
    float s0 = 0.f, s1 = 0.f, s2 = 0.f, s3 = 0.f, s4 = 0.f;
    #pragma unroll
    for (int j = 0; j < 8; j++) {
      s0 = fmaf(e[j], wc[j*5+0], s0);
      s1 = fmaf(e[j], wc[j*5+1], s1);
      s2 = fmaf(e[j], wc[j*5+2], s2);
      s3 = fmaf(e[j], wc[j*5+3], s3);
      s4 = fmaf(e[j], wc[j*5+4], s4);
    }
    #pragma unroll
    for (int off = 1; off < 64; off <<= 1) {
      s0 += __shfl_xor(s0, off); s1 += __shfl_xor(s1, off);
      s2 += __shfl_xor(s2, off); s3 += __shfl_xor(s3, off);
      s4 += __shfl_xor(s4, off);
    }
    float myv = (lane == 0) ? s0 : (lane == 1) ? s1 : (lane == 2) ? s2
              : (lane == 3) ? s3 : (lane == 4) ? s4 : 0.f;
    if (lane < 8) ycp[(size_t)row * 8 + lane] = bf16u(myv);
  }
}

// ---- k_gemm: C[M][128] = A[M][K] @ Bt[128][K]^T  (bf16 MFMA, fp32 accum) ---
// BM=32, BN=64, BK=64; 4 waves 2x2 (wave tile 16x32); XOR-swizzled LDS.
// A_F32: stage A from fp32 source, converting to bf16 on the fly.
template<int KTOT, bool OUTBF, bool A_F32>
__global__ __launch_bounds__(256) void k_gemm(const void* __restrict__ Asrc,
                                              const ushort* __restrict__ Bt,
                                              void* __restrict__ Cout) {
  __shared__ __align__(16) char smem[(32 + 64) * 128];  // A 4KB @0, B 8KB @4096
  const int tid  = threadIdx.x;
  const int lane = tid & 63;
  const int wid  = tid >> 6;
  const int wm = wid >> 1, wn = wid & 1;
  const int rowA0 = (blockIdx.x >> 1) * 32;
  const int bn    = blockIdx.x & 1;

  f32x4 acc[2];
  acc[0] = (f32x4){0.f, 0.f, 0.f, 0.f};
  acc[1] = (f32x4){0.f, 0.f, 0.f, 0.f};

  for (int step = 0; step < KTOT / 64; step++) {
    const int kc = step * 64;
    // stage to regs first (overlap with previous compute)
    uint4 ra;  // 8 bf16 of A
    {
      const int r = tid >> 3, sl = tid & 7;   // 256 slots: 32 rows x 8
      if (A_F32) {
        const float4* ap = (const float4*)((const float*)Asrc +
                            (size_t)(rowA0 + r) * KTOT + kc + sl * 8);
        float4 f0 = ap[0], f1 = ap[1];
        union { ushort us[8]; uint4 q; } pk;
        pk.us[0] = bf16u(f0.x); pk.us[1] = bf16u(f0.y);
        pk.us[2] = bf16u(f0.z); pk.us[3] = bf16u(f0.w);
        pk.us[4] = bf16u(f1.x); pk.us[5] = bf16u(f1.y);
        pk.us[6] = bf16u(f1.z); pk.us[7] = bf16u(f1.w);
        ra = pk.q;
      } else {
        ra = *(const uint4*)((const ushort*)Asrc +
                             (size_t)(rowA0 + r) * KTOT + kc + sl * 8);
      }
    }
    uint4 rb[2];
    #pragma unroll
    for (int i = 0; i < 2; i++) {
      const int slot = tid + i * 256, r = slot >> 3, sl = slot & 7;
      rb[i] = *(const uint4*)(Bt + (size_t)(bn * 64 + r) * KTOT + kc + sl * 8);
    }
    __syncthreads();   // previous compute done before overwrite
    {
      const int r = tid >> 3, sl = tid & 7;
      *(uint4*)(smem + r * 128 + ((sl * 16) ^ ((r & 7) << 4))) = ra;
    }
    #pragma unroll
    for (int i = 0; i < 2; i++) {
      const int slot = tid + i * 256, r = slot >> 3, sl = slot & 7;
      *(uint4*)(smem + 4096 + r * 128 + ((sl * 16) ^ ((r & 7) << 4))) = rb[i];
    }
    __syncthreads();
    #pragma unroll
    for (int kk = 0; kk < 2; kk++) {
      const int cb = kk * 64 + (lane >> 4) * 16;
      const int r = wm * 16 + (lane & 15);
      s16x8 a = *(const s16x8*)(smem + r * 128 + (cb ^ ((r & 7) << 4)));
      #pragma unroll
      for (int n = 0; n < 2; n++) {
        const int rn = wn * 32 + n * 16 + (lane & 15);
        s16x8 b = *(const s16x8*)(smem + 4096 + rn * 128 + (cb ^ ((rn & 7) << 4)));
        acc[n] = __builtin_amdgcn_mfma_f32_16x16x32_bf16(a, b, acc[n], 0, 0, 0);
      }
    }
  }
  // epilogue: row=(lane>>4)*4+reg (M), col=lane&15 (N)
  #pragma unroll
  for (int n = 0; n < 2; n++) {
    #pragma unroll
    for (int reg = 0; reg < 4; reg++) {
      const int grow = rowA0 + wm * 16 + (lane >> 4) * 4 + reg;
      const int gcol = bn * 64 + wn * 32 + n * 16 + (lane & 15);
      if (OUTBF)
        ((ushort*)Cout)[(size_t)grow * 128 + gcol] = bf16u(acc[n][reg]);
      else
        ((float*)Cout)[(size_t)grow * 128 + gcol] = acc[n][reg];
    }
  }
}

// ---- k_mid: wave-per-(t,b); batch-split grid keeps gather set < L2 --------
// blocks 0..1023 -> b=0, blocks 1024..2047 -> b=1. With 4 waves/EU the b=0
// half is resident first, so per-XCD random working set ~2MB < 4MB L2.
__global__ __launch_bounds__(256, 4) void k_mid(
    const ushort* __restrict__ ycp,   // [B][T][8] bf16   (L2-resident, 128KB)
    const ushort* __restrict__ bmb,   // [B][T][MB] bf16  (L2-resident, 2MB/b)
    const ushort* __restrict__ WBb,   // [P][PS*CS] bf16
    const float* __restrict__ Wbias,  // [P]
    const float* __restrict__ Wps1,   // [P][P]
    const int* __restrict__ patches,  // [T][P][PS]  (nt stream)
    const int* __restrict__ pproj,    // [T][P]      (nt stream)
    ushort* __restrict__ obmb)        // [B][T][MB] bf16 (nt stream out)
{
  __shared__ __align__(16) float wps[64 * 64];  // 16KB: Wps1 staged per block
  const int tid  = threadIdx.x;
  const int lane = tid & 63;
  const int wid  = tid >> 6;
  const int b    = blockIdx.x >> 10;            // batch from block id
  const int t    = (blockIdx.x & 1023) * 4 + wid;  // wave-per-t, 0..4095

  for (int j = tid; j < 1024; j += 256)
    ((float4*)wps)[j] = ((const float4*)Wps1)[j];
  __syncthreads();

  // WB row for patch `lane`: 80 bf16 = 40 packed u32 (10 uint4 loads)
  union { unsigned u[40]; uint4 q[10]; } wbu;
  {
    const uint4* src = (const uint4*)(WBb + lane * 80);
    #pragma unroll
    for (int j = 0; j < 10; j++) wbu.q[j] = src[j];
  }
  const float bias = Wbias[lane];

  int idx[16];
  {
    const i32x4* psrc = (const i32x4*)(patches + (size_t)t * P_ * PS_ + lane * PS_);
    #pragma unroll
    for (int j = 0; j < 4; j++) {
      i32x4 v = __builtin_nontemporal_load(psrc + j);
      idx[j*4+0] = v.x; idx[j*4+1] = v.y; idx[j*4+2] = v.z; idx[j*4+3] = v.w;
    }
  }
  const int pp = __builtin_nontemporal_load(pproj + (size_t)t * P_ + lane);

  const ushort* yb = ycp + (size_t)b * T_ * 8;
  // res: gather 16 padded yc rows, dot with bf16 WB row (5 parallel chains)
  float c0 = bias, c1 = 0.f, c2 = 0.f, c3 = 0.f, c4 = 0.f;
  #pragma unroll
  for (int s = 0; s < 16; s++) {
    uint4 g = *(const uint4*)(yb + (size_t)idx[s] * 8);
    const int e = s * 5;  // element base (compile-time)
    const float w0 = ((e+0)&1) ? bf_hi(wbu.u[(e+0)>>1]) : bf_lo(wbu.u[(e+0)>>1]);
    const float w1 = ((e+1)&1) ? bf_hi(wbu.u[(e+1)>>1]) : bf_lo(wbu.u[(e+1)>>1]);
    const float w2 = ((e+2)&1) ? bf_hi(wbu.u[(e+2)>>1]) : bf_lo(wbu.u[(e+2)>>1]);
    const float w3 = ((e+3)&1) ? bf_hi(wbu.u[(e+3)>>1]) : bf_lo(wbu.u[(e+3)>>1]);
    const float w4 = ((e+4)&1) ? bf_hi(wbu.u[(e+4)>>1]) : bf_lo(wbu.u[(e+4)>>1]);
    c0 = fmaf(bf_lo(g.x), w0, c0);
    c1 = fmaf(bf_hi(g.x), w1, c1);
    c2 = fmaf(bf_lo(g.y), w2, c2);
    c3 = fmaf(bf_hi(g.y), w3, c3);
    c4 = fmaf(bf_lo(g.z), w4, c4);
  }
  const float sum = (c0 + c1) + (c2 + c3) + c4;
  // mix[lane] = sum_p res[p] * Wps1[p][lane] (4 chains; Wps1 from LDS)
  float m0 = 0.f, m1 = 0.f, m2 = 0.f, m3 = 0.f;
  #pragma unroll
  for (int p = 0; p < 64; p += 4) {
    m0 = fmaf(rdlane_f(sum, p + 0), wps[(p + 0) * 64 + lane], m0);
    m1 = fmaf(rdlane_f(sum, p + 1), wps[(p + 1) * 64 + lane], m1);
    m2 = fmaf(rdlane_f(sum, p + 2), wps[(p + 2) * 64 + lane], m2);
    m3 = fmaf(rdlane_f(sum, p + 3), wps[(p + 3) * 64 + lane], m3);
  }
  const float mix = (m0 + m1) + (m2 + m3);
  // out[m]: lane handles m = 2*lane, 2*lane+1 (2 parallel chains each)
  const ushort* bb = bmb + (size_t)b * T_ * MB_;
  float oxa = 0.f, oya = 0.f, oxb = 0.f, oyb = 0.f;
  #pragma unroll
  for (int p = 0; p < 64; p += 2) {
    const float mpa = rdlane_f(mix, p);
    const int rowa = __builtin_amdgcn_readlane(pp, p);
    unsigned va = *(const unsigned*)(bb + (size_t)rowa * MB_ + lane * 2);
    oxa = fmaf(bf_lo(va), mpa, oxa);
    oya = fmaf(bf_hi(va), mpa, oya);
    const float mpb = rdlane_f(mix, p + 1);
    const int rowb = __builtin_amdgcn_readlane(pp, p + 1);
    unsigned vb = *(const unsigned*)(bb + (size_t)rowb * MB_ + lane * 2);
    oxb = fmaf(bf_lo(vb), mpb, oxb);
    oyb = fmaf(bf_hi(vb), mpb, oyb);
  }
  unsigned pkd = (unsigned)bf16u(oxa + oxb) | ((unsigned)bf16u(oya + oyb) << 16);
  __builtin_nontemporal_store(pkd,
      (unsigned*)(obmb + ((size_t)b * T_ + t) * MB_ + lane * 2));
}

extern "C" void kernel_launch(void* const* d_in, const int* in_sizes, int n_in,
                              void* d_out, int out_size, void* d_ws, size_t ws_size,
                              hipStream_t stream) {
  const float* y     = (const float*)d_in[0];
  const float* WB    = (const float*)d_in[1];
  const float* Wbias = (const float*)d_in[2];
  const float* Wp2   = (const float*)d_in[3];
  const float* Wpc   = (const float*)d_in[4];
  const float* Wps1  = (const float*)d_in[5];
  const float* WF    = (const float*)d_in[6];
  const int* patches = (const int*)d_in[7];
  const int* pproj   = (const int*)d_in[8];
  float* out = (float*)d_out;

  char* ws = (char*)d_ws;
  ushort* bmb  = (ushort*)(ws);                 // 2 MB    [2][4096][128]
  ushort* obmb = (ushort*)(ws + 2097152);       // 2 MB    [2][4096][128]
  ushort* ycp  = (ushort*)(ws + 4194304);       // 128 KB  [2][4096][8]
  ushort* Wp2T = (ushort*)(ws + 4325376);       // 128 KB  [128][512]
  ushort* WFT  = (ushort*)(ws + 4456448);       // 32 KB   [128][128]
  ushort* WBb  = (ushort*)(ws + 4489216);       // 10 KB   [64][80]

  k_prep<<<dim3(320), dim3(256), 0, stream>>>(y, Wpc, Wp2, WF, WB,
                                              ycp, Wp2T, WFT, WBb);
  k_gemm<512, true,  true ><<<dim3(512), dim3(256), 0, stream>>>((const void*)y, Wp2T, (void*)bmb);
  k_mid <<<dim3(2048), dim3(256), 0, stream>>>(ycp, bmb, WBb, Wbias, Wps1,
                                               patches, pproj, obmb);
  k_gemm<128, false, false><<<dim3(512), dim3(256), 0, stream>>>((const void*)obmb, WFT, (void*)out);
}